// Round 1
// baseline (298.459 us; speedup 1.0000x reference)
//
#include <hip/hip_runtime.h>
#include <stdint.h>

typedef __attribute__((ext_vector_type(8))) short short8;
typedef __attribute__((ext_vector_type(4))) float f32x4;

#define MFMA16 __builtin_amdgcn_mfma_f32_16x16x32_bf16

static constexpr int kNodes = 262144;
static constexpr int kSIn   = 128;
static constexpr int kV     = 64;
static constexpr int kOutD  = 320;

static constexpr int NT      = 64;    // nodes per tile
static constexpr int THREADS = 512;   // 8 waves
static constexpr int NBLOCKS = 256;
static constexpr int TILES   = kNodes / NT;      // 4096
static constexpr int TPB     = TILES / NBLOCKS;  // 16

// ---- LDS byte offsets ----
// weights transposed to [out_ch][k], bf16, XOR-swizzled rows
static constexpr int W1S = 0;        // [192][256B]
static constexpr int W2S = 49152;    // [128][256B]
static constexpr int W1V = 81920;    // [64][128B]   ([j][i])
static constexpr int W2V = 90112;    // [64][128B]   ([j2][j])
static constexpr int XS  = 98304;    // [64][256B]   x_s tile; overlaid by scal
static constexpr int XV  = 114688;   // [192][128B]  x_v tile (rows (n,c)); overlaid by v_g
static constexpr int GT  = 139264;   // [64][128B]   gates bf16
static constexpr int B1O = 147456;   // 192 f32
static constexpr int B2O = 148224;   // 128 f32
static constexpr int SMEM_BYTES = 148736;

__device__ __forceinline__ uint16_t f2bf(float f) {
  uint32_t u = __builtin_bit_cast(uint32_t, f);
  u += 0x7FFFu + ((u >> 16) & 1u);          // round-to-nearest-even
  return (uint16_t)(u >> 16);
}
__device__ __forceinline__ float bf2f(uint16_t u) {
  return __builtin_bit_cast(float, ((uint32_t)u) << 16);
}

extern "C" __global__ __launch_bounds__(THREADS, 2)
void fused_gate_mlp(const float* __restrict__ x_s, const float* __restrict__ x_v,
                    const float* __restrict__ W1_s, const float* __restrict__ b1_s,
                    const float* __restrict__ W1_v, const float* __restrict__ W2_s,
                    const float* __restrict__ b2_s, const float* __restrict__ W2_v,
                    float* __restrict__ out)
{
  extern __shared__ char smem[];
  const int tid = threadIdx.x;

  // ---------- stage weights once per block ----------
  for (int idx = tid; idx < 128 * 192; idx += THREADS) {       // W1_s [k][h] -> [h][k]
    int k = idx / 192, h = idx - k * 192;
    *(uint16_t*)(smem + W1S + h * 256 + ((2 * k) ^ ((h & 7) << 4))) = f2bf(W1_s[idx]);
  }
  for (int idx = tid; idx < 128 * 128; idx += THREADS) {       // W2_s [k][o] -> [o][k]
    int k = idx >> 7, o = idx & 127;
    *(uint16_t*)(smem + W2S + o * 256 + ((2 * k) ^ ((o & 7) << 4))) = f2bf(W2_s[idx]);
  }
  for (int idx = tid; idx < 64 * 64; idx += THREADS) {         // W1_v/W2_v [i][j] -> [j][i]
    int i = idx >> 6, j = idx & 63;
    int off = j * 128 + ((2 * i) ^ ((j & 7) << 4));
    *(uint16_t*)(smem + W1V + off) = f2bf(W1_v[idx]);
    *(uint16_t*)(smem + W2V + off) = f2bf(W2_v[idx]);
  }
  if (tid < 192) ((float*)(smem + B1O))[tid] = b1_s[tid];
  if (tid < 128) ((float*)(smem + B2O))[tid] = b2_s[tid];

  const int w   = tid >> 6;          // wave 0..7
  const int l   = tid & 63;
  const int lw  = l & 15;
  const int lg  = l >> 4;
  const int sx  = (lw & 7) << 4;     // read-side swizzle (all tile rows are %16-based)
  const int mt  = w >> 1;            // 0..3  -> node rows mt*16..+15
  const int nh  = w & 1;             // column half
  const int m0  = mt * 16;
  const int rv0 = mt * 48;           // (n,c) row base for vector path

  const float inv_s = 0.08838834764831845f;  // 1/sqrt(128)
  const float inv_v = 0.125f;                // 1/sqrt(64)

  int tile = blockIdx.x;
  float4 pfs[4], pfv[6];
  {
    const float4* ps = (const float4*)(x_s + (size_t)tile * NT * kSIn);
    const float4* pv = (const float4*)(x_v + (size_t)tile * NT * kV * 3);
#pragma unroll
    for (int p = 0; p < 4; ++p) pfs[p] = ps[tid + p * THREADS];
#pragma unroll
    for (int p = 0; p < 6; ++p) pfv[p] = pv[tid + p * THREADS];
  }

  for (int t = 0; t < TPB; ++t) {
    const int node0 = tile * NT;
    __syncthreads();   // previous tile's LDS reads complete; buffers free

    // ---------- stage x tiles (fp32 regs -> bf16 LDS, swizzled) ----------
#pragma unroll
    for (int p = 0; p < 4; ++p) {                 // x_s: [n][k]
      int idx4 = tid + p * THREADS;
      int n = idx4 >> 5;
      int kb2 = (idx4 & 31) * 8;                  // byte offset of 4 bf16
      uint2 v;
      v.x = (uint32_t)f2bf(pfs[p].x) | ((uint32_t)f2bf(pfs[p].y) << 16);
      v.y = (uint32_t)f2bf(pfs[p].z) | ((uint32_t)f2bf(pfs[p].w) << 16);
      *(uint2*)(smem + XS + n * 256 + (kb2 ^ ((n & 7) << 4))) = v;
    }
#pragma unroll
    for (int p = 0; p < 6; ++p) {                 // x_v: [(n*3+c)][i]
      int idx4 = tid + p * THREADS;
      int n = idx4 / 48;
      int f0 = (idx4 - n * 48) * 4;
      float vals[4] = {pfv[p].x, pfv[p].y, pfv[p].z, pfv[p].w};
#pragma unroll
      for (int e = 0; e < 4; ++e) {
        int fe = f0 + e;
        int i = fe / 3;
        int c = fe - i * 3;
        int rr = n * 3 + c;
        *(uint16_t*)(smem + XV + rr * 128 + ((2 * i) ^ ((rr & 7) << 4))) = f2bf(vals[e]);
      }
    }

    // ---------- prefetch next tile (T14: issue early, consume next iter) ----------
    const int ntile = tile + NBLOCKS;
    if (t + 1 < TPB) {
      const float4* ps = (const float4*)(x_s + (size_t)ntile * NT * kSIn);
      const float4* pv = (const float4*)(x_v + (size_t)ntile * NT * kV * 3);
#pragma unroll
      for (int p = 0; p < 4; ++p) pfs[p] = ps[tid + p * THREADS];
#pragma unroll
      for (int p = 0; p < 6; ++p) pfv[p] = pv[tid + p * THREADS];
    }

    __syncthreads();   // staging visible

    // ---------- phase 2a: s1 = x_s @ W1_s ----------
    f32x4 accs[6];
#pragma unroll
    for (int i = 0; i < 6; ++i) accs[i] = (f32x4){0.f, 0.f, 0.f, 0.f};
    const int arow_s = XS + (m0 + lw) * 256;
#pragma unroll
    for (int kt = 0; kt < 4; ++kt) {
      const int kb = kt * 64 + lg * 16;
      short8 a = *(const short8*)(smem + arow_s + (kb ^ sx));
#pragma unroll
      for (int nt = 0; nt < 6; ++nt) {
        const int h = nh * 96 + nt * 16 + lw;
        short8 b = *(const short8*)(smem + W1S + h * 256 + (kb ^ sx));
        accs[nt] = MFMA16(a, b, accs[nt], 0, 0, 0);
      }
    }

    // ---------- phase 2b: v1 = x_v . W1_v ----------
    f32x4 accv[6];
#pragma unroll
    for (int i = 0; i < 6; ++i) accv[i] = (f32x4){0.f, 0.f, 0.f, 0.f};
#pragma unroll
    for (int kt = 0; kt < 2; ++kt) {
      const int kb = kt * 64 + lg * 16;
      short8 av[3];
#pragma unroll
      for (int m2 = 0; m2 < 3; ++m2)
        av[m2] = *(const short8*)(smem + XV + (rv0 + m2 * 16 + lw) * 128 + (kb ^ sx));
#pragma unroll
      for (int jt = 0; jt < 2; ++jt) {
        const int j = nh * 32 + jt * 16 + lw;
        short8 b = *(const short8*)(smem + W1V + j * 128 + (kb ^ sx));
#pragma unroll
        for (int m2 = 0; m2 < 3; ++m2)
          accv[m2 * 2 + jt] = MFMA16(av[m2], b, accv[m2 * 2 + jt], 0, 0, 0);
      }
    }

    __syncthreads();   // all XS/XV fragment reads done

    // ---------- phase 3: silu / sigmoid, write scal (over XS) + gates ----------
    const float* b1 = (const float*)(smem + B1O);
#pragma unroll
    for (int nt = 0; nt < 6; ++nt) {
      const int h = nh * 96 + nt * 16 + lw;
      const float bb = b1[h];
#pragma unroll
      for (int r = 0; r < 4; ++r) {
        const int m = m0 + lg * 4 + r;
        float v = accs[nt][r] * inv_s + bb;
        float sg = 1.0f / (1.0f + __expf(-v));
        if (nh * 96 + nt * 16 < 128) {   // frag-uniform: plain scalars -> silu
          *(uint16_t*)(smem + XS + m * 256 + ((2 * h) ^ ((m & 7) << 4))) = f2bf(v * sg);
        } else {                         // gate scalars -> sigmoid
          *(uint16_t*)(smem + GT + m * 128 + 2 * (h - 128)) = f2bf(sg);
        }
      }
    }

    __syncthreads();   // gates visible to partner wave

    // ---------- phase 4: v_g = v1 * gate (over XV) ----------
#pragma unroll
    for (int m2 = 0; m2 < 3; ++m2) {
#pragma unroll
      for (int jt = 0; jt < 2; ++jt) {
        const int j = nh * 32 + jt * 16 + lw;
#pragma unroll
        for (int r = 0; r < 4; ++r) {
          const int rr = rv0 + m2 * 16 + lg * 4 + r;
          const int nn = rr / 3;
          const float g = bf2f(*(const uint16_t*)(smem + GT + nn * 128 + 2 * j));
          const float vg = accv[m2 * 2 + jt][r] * inv_v * g;
          *(uint16_t*)(smem + XV + rr * 128 + ((2 * j) ^ ((rr & 7) << 4))) = f2bf(vg);
        }
      }
    }

    __syncthreads();   // scal + v_g visible

    // ---------- phase 5a: out_s = scal @ W2_s ----------
    f32x4 acco[4];
#pragma unroll
    for (int i = 0; i < 4; ++i) acco[i] = (f32x4){0.f, 0.f, 0.f, 0.f};
#pragma unroll
    for (int kt = 0; kt < 4; ++kt) {
      const int kb = kt * 64 + lg * 16;
      short8 a = *(const short8*)(smem + arow_s + (kb ^ sx));
#pragma unroll
      for (int ot = 0; ot < 4; ++ot) {
        const int o = nh * 64 + ot * 16 + lw;
        short8 b = *(const short8*)(smem + W2S + o * 256 + (kb ^ sx));
        acco[ot] = MFMA16(a, b, acco[ot], 0, 0, 0);
      }
    }

    // ---------- phase 5b: out_v = v_g . W2_v ----------
    f32x4 accw[6];
#pragma unroll
    for (int i = 0; i < 6; ++i) accw[i] = (f32x4){0.f, 0.f, 0.f, 0.f};
#pragma unroll
    for (int kt = 0; kt < 2; ++kt) {
      const int kb = kt * 64 + lg * 16;
      short8 av[3];
#pragma unroll
      for (int m2 = 0; m2 < 3; ++m2)
        av[m2] = *(const short8*)(smem + XV + (rv0 + m2 * 16 + lw) * 128 + (kb ^ sx));
#pragma unroll
      for (int jt = 0; jt < 2; ++jt) {
        const int j2 = nh * 32 + jt * 16 + lw;
        short8 b = *(const short8*)(smem + W2V + j2 * 128 + (kb ^ sx));
#pragma unroll
        for (int m2 = 0; m2 < 3; ++m2)
          accw[m2 * 2 + jt] = MFMA16(av[m2], b, accw[m2 * 2 + jt], 0, 0, 0);
      }
    }

    // ---------- phase 6: epilogue + global stores ----------
    const float* b2 = (const float*)(smem + B2O);
#pragma unroll
    for (int ot = 0; ot < 4; ++ot) {
      const int o = nh * 64 + ot * 16 + lw;
      const float bb = b2[o];
#pragma unroll
      for (int r = 0; r < 4; ++r) {
        const int m = m0 + lg * 4 + r;
        out[(size_t)(node0 + m) * kOutD + o] = acco[ot][r] * inv_s + bb;
      }
    }
#pragma unroll
    for (int m2 = 0; m2 < 3; ++m2) {
#pragma unroll
      for (int jt = 0; jt < 2; ++jt) {
        const int j2 = nh * 32 + jt * 16 + lw;
#pragma unroll
        for (int r = 0; r < 4; ++r) {
          const int rr = rv0 + m2 * 16 + lg * 4 + r;
          const int nn = rr / 3;
          const int c = rr - nn * 3;
          out[(size_t)(node0 + nn) * kOutD + 128 + j2 * 3 + c] = accw[m2 * 2 + jt][r] * inv_v;
        }
      }
    }

    tile = ntile;
  }
}

extern "C" void kernel_launch(void* const* d_in, const int* in_sizes, int n_in,
                              void* d_out, int out_size, void* d_ws, size_t ws_size,
                              hipStream_t stream) {
  const float* x_s  = (const float*)d_in[0];
  const float* x_v  = (const float*)d_in[1];
  const float* W1_s = (const float*)d_in[2];
  const float* b1_s = (const float*)d_in[3];
  const float* W1_v = (const float*)d_in[4];
  const float* W2_s = (const float*)d_in[5];
  const float* b2_s = (const float*)d_in[6];
  const float* W2_v = (const float*)d_in[7];
  float* o = (float*)d_out;
  hipLaunchKernelGGL(fused_gate_mlp, dim3(NBLOCKS), dim3(THREADS), SMEM_BYTES, stream,
                     x_s, x_v, W1_s, b1_s, W1_v, W2_s, b2_s, W2_v, o);
}